// Round 3
// baseline (19677.440 us; speedup 1.0000x reference)
//
#include <hip/hip_runtime.h>
#include <hip/hip_bf16.h>
#include <stdint.h>

#define B_  4
#define N0  8192
#define S1  4096
#define S2  2048
#define KNB 32

static constexpr float EPS_IN_ = 1e-5f;

// ---------------- FPS (farthest point sampling) ----------------
// One workgroup per batch. Points + running min-dist live in registers.
// Winner (val,idx,coords) carried through shuffle reduction -> 1 barrier/iter.
// d2 must match numpy exactly: (dx*dx + dy*dy) + dz*dz, all round-nearest,
// NO FMA contraction -> enforced with `#pragma clang fp contract(off)`
// (hipcc default is contract=fast-honor-pragmas; __f*_rn alone gets fused!).
template<int N, int NP, bool CHFIRST>
__global__ __launch_bounds__(1024)
void fps_kernel(const float* __restrict__ pts,
                float* __restrict__ fidx_out,   // [B,NP] indices as float
                float* __restrict__ newxyz,     // [B,NP,3]
                float* __restrict__ out_t)      // [B,3,NP]
{
  constexpr int NT = 1024;
  constexpr int PPT = N / NT;
  const int b = blockIdx.x;
  const int tid = threadIdx.x;
  const int lane = tid & 63;
  const int wid = tid >> 6;

  __shared__ float redv[2][16], redx[2][16], redy[2][16], redz[2][16];
  __shared__ int   redi[2][16];
  __shared__ int   sidx[NP];

  const float* base = pts + (size_t)b * 3 * N;  // 3N floats/batch in both layouts
  float px[PPT], py[PPT], pz[PPT], dist[PPT];
#pragma unroll
  for (int j = 0; j < PPT; ++j) {
    int p = tid + j * NT;
    if (CHFIRST) { px[j] = base[p];     py[j] = base[N + p];   pz[j] = base[2*N + p]; }
    else         { px[j] = base[3*p];   py[j] = base[3*p + 1]; pz[j] = base[3*p + 2]; }
    dist[j] = 1e10f;
  }
  float bx, by, bz;
  if (CHFIRST) { bx = base[0]; by = base[N]; bz = base[2*N]; }
  else         { bx = base[0]; by = base[1]; bz = base[2]; }
  if (tid == 0) { sidx[0] = 0; fidx_out[(size_t)b * NP] = 0.f; }

  for (int i = 1; i < NP; ++i) {
    float bv = -1.f; int bi = 0; float cx = bx, cy = by, cz = bz;
#pragma unroll
    for (int j = 0; j < PPT; ++j) {
#pragma clang fp contract(off)
      float dx = px[j] - bx;
      float dy = py[j] - by;
      float dz = pz[j] - bz;
      float d2 = (dx * dx + dy * dy) + dz * dz;   // strict numpy order, no FMA
      float nd = fminf(dist[j], d2);
      dist[j] = nd;
      if (nd > bv) { bv = nd; bi = tid + (j << 10); cx = px[j]; cy = py[j]; cz = pz[j]; }
    }
    // wave butterfly argmax: (val desc, idx asc)
#pragma unroll
    for (int off = 32; off > 0; off >>= 1) {
      float ov = __shfl_xor(bv, off);
      int   oi = __shfl_xor(bi, off);
      float ox = __shfl_xor(cx, off);
      float oy = __shfl_xor(cy, off);
      float oz = __shfl_xor(cz, off);
      if (ov > bv || (ov == bv && oi < bi)) { bv = ov; bi = oi; cx = ox; cy = oy; cz = oz; }
    }
    const int par = i & 1;
    if (lane == 0) {
      redv[par][wid] = bv; redi[par][wid] = bi;
      redx[par][wid] = cx; redy[par][wid] = cy; redz[par][wid] = cz;
    }
    __syncthreads();
    // every wave redundantly reduces the 16 per-wave winners (no 2nd barrier)
    float rv = (lane < 16) ? redv[par][lane] : -2.f;
    int   ri = (lane < 16) ? redi[par][lane] : 0x7fffffff;
    float rx = (lane < 16) ? redx[par][lane] : 0.f;
    float ry = (lane < 16) ? redy[par][lane] : 0.f;
    float rz = (lane < 16) ? redz[par][lane] : 0.f;
#pragma unroll
    for (int off = 8; off > 0; off >>= 1) {
      float ov = __shfl_xor(rv, off);
      int   oi = __shfl_xor(ri, off);
      float ox = __shfl_xor(rx, off);
      float oy = __shfl_xor(ry, off);
      float oz = __shfl_xor(rz, off);
      if (ov > rv || (ov == rv && oi < ri)) { rv = ov; ri = oi; rx = ox; ry = oy; rz = oz; }
    }
    bx = __shfl(rx, 0); by = __shfl(ry, 0); bz = __shfl(rz, 0);
    int wnr = __shfl(ri, 0);
    if (tid == 0) { sidx[i] = wnr; fidx_out[(size_t)b * NP + i] = (float)wnr; }
  }
  __syncthreads();
  // gather selected points: newxyz [B,NP,3] and transposed output [B,3,NP]
  for (int s = tid; s < NP; s += NT) {
    int id = sidx[s];
    float x, y, z;
    if (CHFIRST) { x = base[id];   y = base[N + id];   z = base[2*N + id]; }
    else         { x = base[3*id]; y = base[3*id + 1]; z = base[3*id + 2]; }
    newxyz[((size_t)b * NP + s) * 3 + 0] = x;
    newxyz[((size_t)b * NP + s) * 3 + 1] = y;
    newxyz[((size_t)b * NP + s) * 3 + 2] = z;
    out_t[((size_t)b * 3 + 0) * NP + s] = x;
    out_t[((size_t)b * 3 + 1) * NP + s] = y;
    out_t[((size_t)b * 3 + 2) * NP + s] = z;
  }
}

// ---------------- exact kNN (32 smallest d2, ties by lowest index) ----------------
// One block per query: distances -> LDS float-bit keys, 12-bit-bin histogram
// select, deterministic ordered emit, exact (key,idx) extraction for pivot ties.
template<int N, bool CHFIRST>
__global__ __launch_bounds__(128)
void knn_kernel(const float* __restrict__ pts, const float* __restrict__ query,
                int* __restrict__ nidx, int S)
{
  constexpr int NT = 128;
  constexpr int PPT = N / NT;
  const int q = blockIdx.x, b = blockIdx.y, tid = threadIdx.x;
  __shared__ uint32_t key[N];
  __shared__ uint32_t hist[4096];
  __shared__ uint32_t gsum[NT];
  __shared__ int cnts[NT];
  __shared__ int s_pivot, s_below;
  __shared__ uint32_t wk[2];
  __shared__ int wi[2];

  const float* qp = query + ((size_t)b * S + q) * 3;
  const float qx = qp[0], qy = qp[1], qz = qp[2];
  for (int h = tid; h < 4096; h += NT) hist[h] = 0;
  __syncthreads();
  const float* base = pts + (size_t)b * 3 * N;
  for (int c = 0; c < PPT; ++c) {
    int p = c * NT + tid;
    float x, y, z;
    if (CHFIRST) { x = base[p];     y = base[N + p];   z = base[2*N + p]; }
    else         { x = base[3*p];   y = base[3*p + 1]; z = base[3*p + 2]; }
    float dx = x - qx, dy = y - qy, dz = z - qz;
    float d2 = dx * dx + dy * dy + dz * dz;      // d2 >= 0 -> bits monotone
    uint32_t k = __float_as_uint(d2);
    key[p] = k;
    atomicAdd(&hist[k >> 19], 1u);
  }
  __syncthreads();
  uint32_t ls = 0;
  for (int h = 0; h < 4096 / NT; ++h) ls += hist[tid * (4096 / NT) + h];
  gsum[tid] = ls;
  __syncthreads();
  if (tid == 0) {
    uint32_t cum = 0; int g = 0;
    while (cum + gsum[g] < (uint32_t)KNB) { cum += gsum[g]; ++g; }
    int bin = g * (4096 / NT);
    while (cum + hist[bin] < (uint32_t)KNB) { cum += hist[bin]; ++bin; }
    s_pivot = bin; s_below = (int)cum;
  }
  __syncthreads();
  const uint32_t pivot = (uint32_t)s_pivot;
  const int below = s_below;
  // deterministic ordered emit of all keys strictly below the pivot bin
  int myc = 0;
  for (int c = 0; c < PPT; ++c) {
    int p = c * NT + tid;
    if ((key[p] >> 19) < pivot) ++myc;
  }
  cnts[tid] = myc;
  __syncthreads();
  if (tid == 0) { int run = 0; for (int t = 0; t < NT; ++t) { int v = cnts[t]; cnts[t] = run; run += v; } }
  __syncthreads();
  int* outq = nidx + ((size_t)b * S + q) * KNB;
  int off = cnts[tid];
  for (int c = 0; c < PPT; ++c) {
    int p = c * NT + tid;
    if ((key[p] >> 19) < pivot) outq[off++] = p;
  }
  // remaining picks from the pivot bin: exact (key, idx) min-extraction
  const int r = KNB - below;
  for (int t = 0; t < r; ++t) {
    __syncthreads();
    uint32_t bk = 0xFFFFFFFFu; int bi = N;
    for (int c = 0; c < PPT; ++c) {
      int p = c * NT + tid;
      uint32_t kk = key[p];
      if ((kk & 0x80000000u) == 0 && (kk >> 19) == pivot) {
        if (kk < bk || (kk == bk && p < bi)) { bk = kk; bi = p; }
      }
    }
#pragma unroll
    for (int o = 32; o > 0; o >>= 1) {
      uint32_t ok = __shfl_xor(bk, o);
      int oi = __shfl_xor(bi, o);
      if (ok < bk || (ok == bk && oi < bi)) { bk = ok; bi = oi; }
    }
    if ((tid & 63) == 0) { wk[tid >> 6] = bk; wi[tid >> 6] = bi; }
    __syncthreads();
    if (tid == 0) {
      uint32_t k0 = wk[0]; int i0 = wi[0];
      if (wk[1] < k0 || (wk[1] == k0 && wi[1] < i0)) { k0 = wk[1]; i0 = wi[1]; }
      key[i0] |= 0x80000000u;   // mark taken (bit31 is free: d2 >= 0)
      outq[below + t] = i0;
    }
  }
}

// ---------------- grouping (gather + relative coords) ----------------
__global__ void gather1_kernel(const float* __restrict__ pc, const float* __restrict__ feat,
                               const int* __restrict__ nidx, const float* __restrict__ ctr,
                               __hip_bfloat16* __restrict__ g)   // [B][S1*K][6]
{
  int e = blockIdx.x * 256 + threadIdx.x;
  int b = blockIdx.y;
  if (e >= S1 * KNB) return;
  int s = e >> 5;
  int n = nidx[((size_t)b * S1 + s) * KNB + (e & 31)];
  const float* pb = pc + (size_t)b * 3 * N0;
  const float* fb = feat + (size_t)b * 3 * N0;
  const float* c = ctr + ((size_t)b * S1 + s) * 3;
  __hip_bfloat16* o = g + ((size_t)b * S1 * KNB + e) * 6;
  o[0] = __float2bfloat16(pb[n] - c[0]);
  o[1] = __float2bfloat16(pb[N0 + n] - c[1]);
  o[2] = __float2bfloat16(pb[2 * N0 + n] - c[2]);
  o[3] = __float2bfloat16(fb[n]);
  o[4] = __float2bfloat16(fb[N0 + n]);
  o[5] = __float2bfloat16(fb[2 * N0 + n]);
}

__global__ void gather2_kernel(const float* __restrict__ pc1, const float* __restrict__ f1,
                               const int* __restrict__ nidx, const float* __restrict__ ctr,
                               __hip_bfloat16* __restrict__ g)   // [B][S2*K][35]
{
  int e = blockIdx.x * 256 + threadIdx.x;
  int b = blockIdx.y;
  if (e >= S2 * KNB) return;
  int s = e >> 5;
  int n = nidx[((size_t)b * S2 + s) * KNB + (e & 31)];
  const float* p = pc1 + ((size_t)b * S1 + n) * 3;
  const float* c = ctr + ((size_t)b * S2 + s) * 3;
  const float* f = f1 + ((size_t)b * S1 + n) * 32;
  __hip_bfloat16* o = g + ((size_t)b * S2 * KNB + e) * 35;
  o[0] = __float2bfloat16(p[0] - c[0]);
  o[1] = __float2bfloat16(p[1] - c[1]);
  o[2] = __float2bfloat16(p[2] - c[2]);
#pragma unroll
  for (int ci = 0; ci < 32; ++ci) o[3 + ci] = __float2bfloat16(f[ci]);
}

// ---------------- 1x1-conv linear layer + stats partials ----------------
template<int CIN, int COUT, int TY, int EPT>
__global__ __launch_bounds__(256)
void linear_kernel(const __hip_bfloat16* __restrict__ x, const float* __restrict__ w,
                   const float* __restrict__ bias, __hip_bfloat16* __restrict__ out,
                   float* __restrict__ psum, float* __restrict__ psq, int elems)
{
  const int co = threadIdx.x, ty = threadIdx.y;
  const int blk = blockIdx.x, b = blockIdx.y;
  float wr[CIN];
#pragma unroll
  for (int ci = 0; ci < CIN; ++ci) wr[ci] = w[co * CIN + ci];
  const float bsv = bias[co];
  float ssum = 0.f, ssq = 0.f;
  const int e0 = blk * (TY * EPT) + ty * EPT;
  const __hip_bfloat16* xb = x + (size_t)b * elems * CIN;
  __hip_bfloat16* ob = out + (size_t)b * elems * COUT;
  for (int t = 0; t < EPT; ++t) {
    const int e = e0 + t;
    float acc = bsv;
#pragma unroll
    for (int ci = 0; ci < CIN; ++ci)
      acc += wr[ci] * __bfloat162float(xb[(size_t)e * CIN + ci]);
    ob[(size_t)e * COUT + co] = __float2bfloat16(acc);
    ssum += acc; ssq += acc * acc;
  }
  __shared__ float r1[TY][COUT], r2[TY][COUT];
  r1[ty][co] = ssum; r2[ty][co] = ssq;
  __syncthreads();
  if (ty == 0) {
    float a = 0.f, c = 0.f;
#pragma unroll
    for (int y = 0; y < TY; ++y) { a += r1[y][co]; c += r2[y][co]; }
    psum[((size_t)b * gridDim.x + blk) * COUT + co] = a;
    psq [((size_t)b * gridDim.x + blk) * COUT + co] = c;
  }
}

template<int COUT>
__global__ void stats_kernel(const float* __restrict__ psum, const float* __restrict__ psq,
                             int nblk, float invcnt, float* __restrict__ mean, float* __restrict__ rsv)
{
  int i = threadIdx.x;
  if (i >= B_ * COUT) return;
  int b = i / COUT, co = i % COUT;
  float s = 0.f, qq = 0.f;
  for (int k = 0; k < nblk; ++k) {
    s  += psum[((size_t)b * nblk + k) * COUT + co];
    qq += psq [((size_t)b * nblk + k) * COUT + co];
  }
  float m = s * invcnt;
  float v = qq * invcnt - m * m;
  mean[i] = m;
  rsv[i] = rsqrtf(fmaxf(v, 0.f) + EPS_IN_);
}

template<int COUT>
__global__ __launch_bounds__(256)
void norm_relu_kernel(__hip_bfloat16* __restrict__ buf, const float* __restrict__ mean,
                      const float* __restrict__ rsv, int total)
{
  const int b = blockIdx.y;
  __hip_bfloat16* bb = buf + (size_t)b * total;
  const float* mb = mean + b * COUT;
  const float* rb = rsv + b * COUT;
  for (int p = blockIdx.x * 256 + threadIdx.x; p < total; p += gridDim.x * 256) {
    int co = p & (COUT - 1);
    float v = __bfloat162float(bb[p]);
    v = fmaxf(0.f, (v - mb[co]) * rb[co]);
    bb[p] = __float2bfloat16(v);
  }
}

// ---------------- max-pool over nsample ----------------
__global__ void pool1_kernel(const __hip_bfloat16* __restrict__ buf, float* __restrict__ f1)
{
  int i = blockIdx.x * 256 + threadIdx.x;   // s*32+co
  int b = blockIdx.y;
  if (i >= S1 * 32) return;
  int s = i >> 5, co = i & 31;
  const __hip_bfloat16* bb = buf + ((size_t)b * S1 * KNB + (size_t)s * KNB) * 32 + co;
  float best = -3.4e38f;
  for (int j = 0; j < KNB; ++j) best = fmaxf(best, __bfloat162float(bb[j * 32]));
  f1[((size_t)b * S1 + s) * 32 + co] = best;
}

__global__ void pool2_kernel(const __hip_bfloat16* __restrict__ buf, float* __restrict__ out2)
{
  int i = blockIdx.x * 256 + threadIdx.x;   // s*64+co
  int b = blockIdx.y;
  if (i >= S2 * 64) return;
  int s = i >> 6, co = i & 63;
  const __hip_bfloat16* bb = buf + ((size_t)b * S2 * KNB + (size_t)s * KNB) * 64 + co;
  float best = -3.4e38f;
  for (int j = 0; j < KNB; ++j) best = fmaxf(best, __bfloat162float(bb[j * 64]));
  out2[((size_t)b * 64 + co) * S2 + s] = best;   // [B,64,S2] transposed
}

extern "C" void kernel_launch(void* const* d_in, const int* in_sizes, int n_in,
                              void* d_out, int out_size, void* d_ws, size_t ws_size,
                              hipStream_t stream)
{
  (void)in_sizes; (void)n_in; (void)out_size; (void)ws_size;
  const float* pc   = (const float*)d_in[0];
  const float* feat = (const float*)d_in[1];
  const float* w1a = (const float*)d_in[2];  const float* b1a = (const float*)d_in[3];
  const float* w1b = (const float*)d_in[4];  const float* b1b = (const float*)d_in[5];
  const float* w1c = (const float*)d_in[6];  const float* b1c = (const float*)d_in[7];
  const float* w2a = (const float*)d_in[8];  const float* b2a = (const float*)d_in[9];
  const float* w2b = (const float*)d_in[10]; const float* b2b = (const float*)d_in[11];
  const float* w2c = (const float*)d_in[12]; const float* b2c = (const float*)d_in[13];

  float* out  = (float*)d_out;
  float* out0 = out;                 // pc1^T [4,3,4096]
  float* out1 = out + 49152;         // pc2^T [4,3,2048]
  float* out2 = out + 73728;         // f2^T  [4,64,2048]
  float* out3 = out + 598016;        // idx1  [4,4096] (as float)
  float* out4 = out + 614400;        // idx2  [4,2048] (as float)

  char* wp = (char*)d_ws;
  auto carve = [&](size_t bytes) { char* p = wp; wp += (bytes + 255) & ~(size_t)255; return p; };
  __hip_bfloat16* bufA = (__hip_bfloat16*)carve((size_t)B_ * S1 * KNB * 32 * 2);
  __hip_bfloat16* bufB = (__hip_bfloat16*)carve((size_t)B_ * S1 * KNB * 32 * 2);
  int*   nidx1 = (int*)carve((size_t)B_ * S1 * KNB * 4);
  int*   nidx2 = (int*)carve((size_t)B_ * S2 * KNB * 4);
  float* pc1   = (float*)carve((size_t)B_ * S1 * 3 * 4);
  float* pc2   = (float*)carve((size_t)B_ * S2 * 3 * 4);
  float* f1    = (float*)carve((size_t)B_ * S1 * 32 * 4);
  float* psum  = (float*)carve((size_t)B_ * 512 * 64 * 4);
  float* psq   = (float*)carve((size_t)B_ * 512 * 64 * 4);
  float* mean  = (float*)carve((size_t)B_ * 64 * 4);
  float* rsv   = (float*)carve((size_t)B_ * 64 * 4);

  // ---- stage 1 ----
  fps_kernel<N0, S1, true><<<B_, 1024, 0, stream>>>(pc, out3, pc1, out0);
  knn_kernel<N0, true><<<dim3(S1, B_), 128, 0, stream>>>(pc, pc1, nidx1, S1);
  gather1_kernel<<<dim3(S1 * KNB / 256, B_), 256, 0, stream>>>(pc, feat, nidx1, pc1, bufA);
  linear_kernel<6, 32, 8, 32><<<dim3(512, B_), dim3(32, 8), 0, stream>>>(bufA, w1a, b1a, bufB, psum, psq, S1 * KNB);
  stats_kernel<32><<<1, 256, 0, stream>>>(psum, psq, 512, 1.f / (S1 * KNB), mean, rsv);
  norm_relu_kernel<32><<<dim3(2048, B_), 256, 0, stream>>>(bufB, mean, rsv, S1 * KNB * 32);
  linear_kernel<32, 32, 8, 32><<<dim3(512, B_), dim3(32, 8), 0, stream>>>(bufB, w1b, b1b, bufA, psum, psq, S1 * KNB);
  stats_kernel<32><<<1, 256, 0, stream>>>(psum, psq, 512, 1.f / (S1 * KNB), mean, rsv);
  norm_relu_kernel<32><<<dim3(2048, B_), 256, 0, stream>>>(bufA, mean, rsv, S1 * KNB * 32);
  linear_kernel<32, 32, 8, 32><<<dim3(512, B_), dim3(32, 8), 0, stream>>>(bufA, w1c, b1c, bufB, psum, psq, S1 * KNB);
  stats_kernel<32><<<1, 256, 0, stream>>>(psum, psq, 512, 1.f / (S1 * KNB), mean, rsv);
  norm_relu_kernel<32><<<dim3(2048, B_), 256, 0, stream>>>(bufB, mean, rsv, S1 * KNB * 32);
  pool1_kernel<<<dim3(512, B_), 256, 0, stream>>>(bufB, f1);

  // ---- stage 2 ----
  fps_kernel<S1, S2, false><<<B_, 1024, 0, stream>>>(pc1, out4, pc2, out1);
  knn_kernel<S1, false><<<dim3(S2, B_), 128, 0, stream>>>(pc1, pc2, nidx2, S2);
  gather2_kernel<<<dim3(S2 * KNB / 256, B_), 256, 0, stream>>>(pc1, f1, nidx2, pc2, bufA);
  linear_kernel<35, 64, 4, 32><<<dim3(512, B_), dim3(64, 4), 0, stream>>>(bufA, w2a, b2a, bufB, psum, psq, S2 * KNB);
  stats_kernel<64><<<1, 256, 0, stream>>>(psum, psq, 512, 1.f / (S2 * KNB), mean, rsv);
  norm_relu_kernel<64><<<dim3(2048, B_), 256, 0, stream>>>(bufB, mean, rsv, S2 * KNB * 64);
  linear_kernel<64, 64, 4, 32><<<dim3(512, B_), dim3(64, 4), 0, stream>>>(bufB, w2b, b2b, bufA, psum, psq, S2 * KNB);
  stats_kernel<64><<<1, 256, 0, stream>>>(psum, psq, 512, 1.f / (S2 * KNB), mean, rsv);
  norm_relu_kernel<64><<<dim3(2048, B_), 256, 0, stream>>>(bufA, mean, rsv, S2 * KNB * 64);
  linear_kernel<64, 64, 4, 32><<<dim3(512, B_), dim3(64, 4), 0, stream>>>(bufA, w2c, b2c, bufB, psum, psq, S2 * KNB);
  stats_kernel<64><<<1, 256, 0, stream>>>(psum, psq, 512, 1.f / (S2 * KNB), mean, rsv);
  norm_relu_kernel<64><<<dim3(2048, B_), 256, 0, stream>>>(bufB, mean, rsv, S2 * KNB * 64);
  pool2_kernel<<<dim3(512, B_), 256, 0, stream>>>(bufB, out2);
}

// Round 4
// 8460.771 us; speedup vs baseline: 2.3257x; 2.3257x over previous
//
#include <hip/hip_runtime.h>
#include <hip/hip_bf16.h>
#include <stdint.h>

#define B_  4
#define N0  8192
#define S1  4096
#define S2  2048
#define KNB 32

static constexpr float EPS_IN_ = 1e-5f;

// ---------------- FPS (farthest point sampling) ----------------
// One workgroup per batch (serial argmax chain -> single-CU latency bound).
// Value-only max reduction; argmax recovered by exact bit-equality scan +
// LDS atomicMin (numpy first-max tie-break). Coords live in an LDS table so
// the winner's coords are broadcast reads, not shuffle payload.
// d2 must match numpy exactly: (dx*dx + dy*dy) + dz*dz, all round-nearest,
// NO FMA contraction -> `#pragma clang fp contract(off)` (hipcc default is
// contract=fast-honor-pragmas; __f*_rn alone gets fused!).
template<int N, int NP, bool CHFIRST>
__global__ __launch_bounds__(512)
void fps_kernel(const float* __restrict__ pts,
                float* __restrict__ fidx_out,   // [B,NP] indices as float
                float* __restrict__ newxyz,     // [B,NP,3]
                float* __restrict__ out_t)      // [B,3,NP]
{
  constexpr int NT = 512;
  constexpr int PPT = N / NT;
  constexpr int NW = NT / 64;   // 8 waves
  const int b = blockIdx.x;
  const int tid = threadIdx.x;
  const int lane = tid & 63;
  const int wid = tid >> 6;

  __shared__ float lx[N], ly[N], lz[N];
  __shared__ float redv[2][NW];
  __shared__ int   widx[2];
  __shared__ int   sidx[NP];

  const float* base = pts + (size_t)b * 3 * N;  // 3N floats/batch in both layouts
  float px[PPT], py[PPT], pz[PPT], dist[PPT];
#pragma unroll
  for (int j = 0; j < PPT; ++j) {
    int p = tid + j * NT;
    float x, y, z;
    if (CHFIRST) { x = base[p];     y = base[N + p];   z = base[2*N + p]; }
    else         { x = base[3*p];   y = base[3*p + 1]; z = base[3*p + 2]; }
    px[j] = x; py[j] = y; pz[j] = z;
    lx[p] = x; ly[p] = y; lz[p] = z;
    dist[j] = 1e10f;
  }
  if (tid == 0) {
    widx[0] = 0x7fffffff; widx[1] = 0x7fffffff;
    sidx[0] = 0; fidx_out[(size_t)b * NP] = 0.f;
  }
  __syncthreads();
  float bx = lx[0], by = ly[0], bz = lz[0];

  for (int i = 1; i < NP; ++i) {
    const int par = i & 1;
    // ---- phase A: dist update + value-only max ----
    float mx = -1.f;
#pragma unroll
    for (int j = 0; j < PPT; ++j) {
#pragma clang fp contract(off)
      float dx = px[j] - bx;
      float dy = py[j] - by;
      float dz = pz[j] - bz;
      float d2 = (dx * dx + dy * dy) + dz * dz;   // strict numpy order, no FMA
      float nd = fminf(dist[j], d2);
      dist[j] = nd;
      mx = fmaxf(mx, nd);
    }
    float wmx = mx;
#pragma unroll
    for (int off = 32; off; off >>= 1) wmx = fmaxf(wmx, __shfl_xor(wmx, off));
    if (lane == 0) redv[par][wid] = wmx;
    __syncthreads();   // barrier 1: per-wave maxes visible

    // ---- phase B: global max (redundant per thread) + argmax recovery ----
    float gmx = redv[par][0];
#pragma unroll
    for (int w = 1; w < NW; ++w) gmx = fmaxf(gmx, redv[par][w]);
    if (tid == 0) widx[par ^ 1] = 0x7fffffff;   // reset other-parity slot (safe: last read before barrier1)
    if (mx == gmx) {                            // max is exact -> equality recovery is exact
      int ci = 0x7fffffff;
#pragma unroll
      for (int j = 0; j < PPT; ++j)
        if (dist[j] == gmx) ci = min(ci, tid + j * NT);
      atomicMin(&widx[par], ci);
    }
    __syncthreads();   // barrier 2: winner index visible

    const int wi = widx[par];
    bx = lx[wi]; by = ly[wi]; bz = lz[wi];      // broadcast LDS reads
    if (tid == 0) { sidx[i] = wi; fidx_out[(size_t)b * NP + i] = (float)wi; }
  }
  __syncthreads();
  // gather selected points: newxyz [B,NP,3] and transposed output [B,3,NP]
  for (int s = tid; s < NP; s += NT) {
    int id = sidx[s];
    float x = lx[id], y = ly[id], z = lz[id];
    newxyz[((size_t)b * NP + s) * 3 + 0] = x;
    newxyz[((size_t)b * NP + s) * 3 + 1] = y;
    newxyz[((size_t)b * NP + s) * 3 + 2] = z;
    out_t[((size_t)b * 3 + 0) * NP + s] = x;
    out_t[((size_t)b * 3 + 1) * NP + s] = y;
    out_t[((size_t)b * 3 + 2) * NP + s] = z;
  }
}

// ---------------- exact kNN (32 smallest d2, ties by lowest index) ----------------
// One block per query: distances -> LDS float-bit keys, 12-bit-bin histogram
// select, deterministic ordered emit, exact (key,idx) extraction for pivot ties.
template<int N, bool CHFIRST>
__global__ __launch_bounds__(128)
void knn_kernel(const float* __restrict__ pts, const float* __restrict__ query,
                int* __restrict__ nidx, int S)
{
  constexpr int NT = 128;
  constexpr int PPT = N / NT;
  const int q = blockIdx.x, b = blockIdx.y, tid = threadIdx.x;
  __shared__ uint32_t key[N];
  __shared__ uint32_t hist[4096];
  __shared__ uint32_t gsum[NT];
  __shared__ int cnts[NT];
  __shared__ int s_pivot, s_below;
  __shared__ uint32_t wk[2];
  __shared__ int wi[2];

  const float* qp = query + ((size_t)b * S + q) * 3;
  const float qx = qp[0], qy = qp[1], qz = qp[2];
  for (int h = tid; h < 4096; h += NT) hist[h] = 0;
  __syncthreads();
  const float* base = pts + (size_t)b * 3 * N;
  for (int c = 0; c < PPT; ++c) {
    int p = c * NT + tid;
    float x, y, z;
    if (CHFIRST) { x = base[p];     y = base[N + p];   z = base[2*N + p]; }
    else         { x = base[3*p];   y = base[3*p + 1]; z = base[3*p + 2]; }
    float dx = x - qx, dy = y - qy, dz = z - qz;
    float d2 = dx * dx + dy * dy + dz * dz;      // d2 >= 0 -> bits monotone
    uint32_t k = __float_as_uint(d2);
    key[p] = k;
    atomicAdd(&hist[k >> 19], 1u);
  }
  __syncthreads();
  uint32_t ls = 0;
  for (int h = 0; h < 4096 / NT; ++h) ls += hist[tid * (4096 / NT) + h];
  gsum[tid] = ls;
  __syncthreads();
  if (tid == 0) {
    uint32_t cum = 0; int g = 0;
    while (cum + gsum[g] < (uint32_t)KNB) { cum += gsum[g]; ++g; }
    int bin = g * (4096 / NT);
    while (cum + hist[bin] < (uint32_t)KNB) { cum += hist[bin]; ++bin; }
    s_pivot = bin; s_below = (int)cum;
  }
  __syncthreads();
  const uint32_t pivot = (uint32_t)s_pivot;
  const int below = s_below;
  // deterministic ordered emit of all keys strictly below the pivot bin
  int myc = 0;
  for (int c = 0; c < PPT; ++c) {
    int p = c * NT + tid;
    if ((key[p] >> 19) < pivot) ++myc;
  }
  cnts[tid] = myc;
  __syncthreads();
  if (tid == 0) { int run = 0; for (int t = 0; t < NT; ++t) { int v = cnts[t]; cnts[t] = run; run += v; } }
  __syncthreads();
  int* outq = nidx + ((size_t)b * S + q) * KNB;
  int off = cnts[tid];
  for (int c = 0; c < PPT; ++c) {
    int p = c * NT + tid;
    if ((key[p] >> 19) < pivot) outq[off++] = p;
  }
  // remaining picks from the pivot bin: exact (key, idx) min-extraction
  const int r = KNB - below;
  for (int t = 0; t < r; ++t) {
    __syncthreads();
    uint32_t bk = 0xFFFFFFFFu; int bi = N;
    for (int c = 0; c < PPT; ++c) {
      int p = c * NT + tid;
      uint32_t kk = key[p];
      if ((kk & 0x80000000u) == 0 && (kk >> 19) == pivot) {
        if (kk < bk || (kk == bk && p < bi)) { bk = kk; bi = p; }
      }
    }
#pragma unroll
    for (int o = 32; o > 0; o >>= 1) {
      uint32_t ok = __shfl_xor(bk, o);
      int oi = __shfl_xor(bi, o);
      if (ok < bk || (ok == bk && oi < bi)) { bk = ok; bi = oi; }
    }
    if ((tid & 63) == 0) { wk[tid >> 6] = bk; wi[tid >> 6] = bi; }
    __syncthreads();
    if (tid == 0) {
      uint32_t k0 = wk[0]; int i0 = wi[0];
      if (wk[1] < k0 || (wk[1] == k0 && wi[1] < i0)) { k0 = wk[1]; i0 = wi[1]; }
      key[i0] |= 0x80000000u;   // mark taken (bit31 is free: d2 >= 0)
      outq[below + t] = i0;
    }
  }
}

// ---------------- grouping (gather + relative coords) ----------------
__global__ void gather1_kernel(const float* __restrict__ pc, const float* __restrict__ feat,
                               const int* __restrict__ nidx, const float* __restrict__ ctr,
                               __hip_bfloat16* __restrict__ g)   // [B][S1*K][6]
{
  int e = blockIdx.x * 256 + threadIdx.x;
  int b = blockIdx.y;
  if (e >= S1 * KNB) return;
  int s = e >> 5;
  int n = nidx[((size_t)b * S1 + s) * KNB + (e & 31)];
  const float* pb = pc + (size_t)b * 3 * N0;
  const float* fb = feat + (size_t)b * 3 * N0;
  const float* c = ctr + ((size_t)b * S1 + s) * 3;
  __hip_bfloat16* o = g + ((size_t)b * S1 * KNB + e) * 6;
  o[0] = __float2bfloat16(pb[n] - c[0]);
  o[1] = __float2bfloat16(pb[N0 + n] - c[1]);
  o[2] = __float2bfloat16(pb[2 * N0 + n] - c[2]);
  o[3] = __float2bfloat16(fb[n]);
  o[4] = __float2bfloat16(fb[N0 + n]);
  o[5] = __float2bfloat16(fb[2 * N0 + n]);
}

__global__ void gather2_kernel(const float* __restrict__ pc1, const float* __restrict__ f1,
                               const int* __restrict__ nidx, const float* __restrict__ ctr,
                               __hip_bfloat16* __restrict__ g)   // [B][S2*K][35]
{
  int e = blockIdx.x * 256 + threadIdx.x;
  int b = blockIdx.y;
  if (e >= S2 * KNB) return;
  int s = e >> 5;
  int n = nidx[((size_t)b * S2 + s) * KNB + (e & 31)];
  const float* p = pc1 + ((size_t)b * S1 + n) * 3;
  const float* c = ctr + ((size_t)b * S2 + s) * 3;
  const float* f = f1 + ((size_t)b * S1 + n) * 32;
  __hip_bfloat16* o = g + ((size_t)b * S2 * KNB + e) * 35;
  o[0] = __float2bfloat16(p[0] - c[0]);
  o[1] = __float2bfloat16(p[1] - c[1]);
  o[2] = __float2bfloat16(p[2] - c[2]);
#pragma unroll
  for (int ci = 0; ci < 32; ++ci) o[3 + ci] = __float2bfloat16(f[ci]);
}

// ---------------- 1x1-conv linear layer + stats partials ----------------
template<int CIN, int COUT, int TY, int EPT>
__global__ __launch_bounds__(256)
void linear_kernel(const __hip_bfloat16* __restrict__ x, const float* __restrict__ w,
                   const float* __restrict__ bias, __hip_bfloat16* __restrict__ out,
                   float* __restrict__ psum, float* __restrict__ psq, int elems)
{
  const int co = threadIdx.x, ty = threadIdx.y;
  const int blk = blockIdx.x, b = blockIdx.y;
  float wr[CIN];
#pragma unroll
  for (int ci = 0; ci < CIN; ++ci) wr[ci] = w[co * CIN + ci];
  const float bsv = bias[co];
  float ssum = 0.f, ssq = 0.f;
  const int e0 = blk * (TY * EPT) + ty * EPT;
  const __hip_bfloat16* xb = x + (size_t)b * elems * CIN;
  __hip_bfloat16* ob = out + (size_t)b * elems * COUT;
  for (int t = 0; t < EPT; ++t) {
    const int e = e0 + t;
    float acc = bsv;
#pragma unroll
    for (int ci = 0; ci < CIN; ++ci)
      acc += wr[ci] * __bfloat162float(xb[(size_t)e * CIN + ci]);
    ob[(size_t)e * COUT + co] = __float2bfloat16(acc);
    ssum += acc; ssq += acc * acc;
  }
  __shared__ float r1[TY][COUT], r2[TY][COUT];
  r1[ty][co] = ssum; r2[ty][co] = ssq;
  __syncthreads();
  if (ty == 0) {
    float a = 0.f, c = 0.f;
#pragma unroll
    for (int y = 0; y < TY; ++y) { a += r1[y][co]; c += r2[y][co]; }
    psum[((size_t)b * gridDim.x + blk) * COUT + co] = a;
    psq [((size_t)b * gridDim.x + blk) * COUT + co] = c;
  }
}

template<int COUT>
__global__ void stats_kernel(const float* __restrict__ psum, const float* __restrict__ psq,
                             int nblk, float invcnt, float* __restrict__ mean, float* __restrict__ rsv)
{
  int i = threadIdx.x;
  if (i >= B_ * COUT) return;
  int b = i / COUT, co = i % COUT;
  float s = 0.f, qq = 0.f;
  for (int k = 0; k < nblk; ++k) {
    s  += psum[((size_t)b * nblk + k) * COUT + co];
    qq += psq [((size_t)b * nblk + k) * COUT + co];
  }
  float m = s * invcnt;
  float v = qq * invcnt - m * m;
  mean[i] = m;
  rsv[i] = rsqrtf(fmaxf(v, 0.f) + EPS_IN_);
}

template<int COUT>
__global__ __launch_bounds__(256)
void norm_relu_kernel(__hip_bfloat16* __restrict__ buf, const float* __restrict__ mean,
                      const float* __restrict__ rsv, int total)
{
  const int b = blockIdx.y;
  __hip_bfloat16* bb = buf + (size_t)b * total;
  const float* mb = mean + b * COUT;
  const float* rb = rsv + b * COUT;
  for (int p = blockIdx.x * 256 + threadIdx.x; p < total; p += gridDim.x * 256) {
    int co = p & (COUT - 1);
    float v = __bfloat162float(bb[p]);
    v = fmaxf(0.f, (v - mb[co]) * rb[co]);
    bb[p] = __float2bfloat16(v);
  }
}

// ---------------- max-pool over nsample ----------------
__global__ void pool1_kernel(const __hip_bfloat16* __restrict__ buf, float* __restrict__ f1)
{
  int i = blockIdx.x * 256 + threadIdx.x;   // s*32+co
  int b = blockIdx.y;
  if (i >= S1 * 32) return;
  int s = i >> 5, co = i & 31;
  const __hip_bfloat16* bb = buf + ((size_t)b * S1 * KNB + (size_t)s * KNB) * 32 + co;
  float best = -3.4e38f;
  for (int j = 0; j < KNB; ++j) best = fmaxf(best, __bfloat162float(bb[j * 32]));
  f1[((size_t)b * S1 + s) * 32 + co] = best;
}

__global__ void pool2_kernel(const __hip_bfloat16* __restrict__ buf, float* __restrict__ out2)
{
  int i = blockIdx.x * 256 + threadIdx.x;   // s*64+co
  int b = blockIdx.y;
  if (i >= S2 * 64) return;
  int s = i >> 6, co = i & 63;
  const __hip_bfloat16* bb = buf + ((size_t)b * S2 * KNB + (size_t)s * KNB) * 64 + co;
  float best = -3.4e38f;
  for (int j = 0; j < KNB; ++j) best = fmaxf(best, __bfloat162float(bb[j * 64]));
  out2[((size_t)b * 64 + co) * S2 + s] = best;   // [B,64,S2] transposed
}

extern "C" void kernel_launch(void* const* d_in, const int* in_sizes, int n_in,
                              void* d_out, int out_size, void* d_ws, size_t ws_size,
                              hipStream_t stream)
{
  (void)in_sizes; (void)n_in; (void)out_size; (void)ws_size;
  const float* pc   = (const float*)d_in[0];
  const float* feat = (const float*)d_in[1];
  const float* w1a = (const float*)d_in[2];  const float* b1a = (const float*)d_in[3];
  const float* w1b = (const float*)d_in[4];  const float* b1b = (const float*)d_in[5];
  const float* w1c = (const float*)d_in[6];  const float* b1c = (const float*)d_in[7];
  const float* w2a = (const float*)d_in[8];  const float* b2a = (const float*)d_in[9];
  const float* w2b = (const float*)d_in[10]; const float* b2b = (const float*)d_in[11];
  const float* w2c = (const float*)d_in[12]; const float* b2c = (const float*)d_in[13];

  float* out  = (float*)d_out;
  float* out0 = out;                 // pc1^T [4,3,4096]
  float* out1 = out + 49152;         // pc2^T [4,3,2048]
  float* out2 = out + 73728;         // f2^T  [4,64,2048]
  float* out3 = out + 598016;        // idx1  [4,4096] (as float)
  float* out4 = out + 614400;        // idx2  [4,2048] (as float)

  char* wp = (char*)d_ws;
  auto carve = [&](size_t bytes) { char* p = wp; wp += (bytes + 255) & ~(size_t)255; return p; };
  __hip_bfloat16* bufA = (__hip_bfloat16*)carve((size_t)B_ * S1 * KNB * 32 * 2);
  __hip_bfloat16* bufB = (__hip_bfloat16*)carve((size_t)B_ * S1 * KNB * 32 * 2);
  int*   nidx1 = (int*)carve((size_t)B_ * S1 * KNB * 4);
  int*   nidx2 = (int*)carve((size_t)B_ * S2 * KNB * 4);
  float* pc1   = (float*)carve((size_t)B_ * S1 * 3 * 4);
  float* pc2   = (float*)carve((size_t)B_ * S2 * 3 * 4);
  float* f1    = (float*)carve((size_t)B_ * S1 * 32 * 4);
  float* psum  = (float*)carve((size_t)B_ * 512 * 64 * 4);
  float* psq   = (float*)carve((size_t)B_ * 512 * 64 * 4);
  float* mean  = (float*)carve((size_t)B_ * 64 * 4);
  float* rsv   = (float*)carve((size_t)B_ * 64 * 4);

  // ---- stage 1 ----
  fps_kernel<N0, S1, true><<<B_, 512, 0, stream>>>(pc, out3, pc1, out0);
  knn_kernel<N0, true><<<dim3(S1, B_), 128, 0, stream>>>(pc, pc1, nidx1, S1);
  gather1_kernel<<<dim3(S1 * KNB / 256, B_), 256, 0, stream>>>(pc, feat, nidx1, pc1, bufA);
  linear_kernel<6, 32, 8, 32><<<dim3(512, B_), dim3(32, 8), 0, stream>>>(bufA, w1a, b1a, bufB, psum, psq, S1 * KNB);
  stats_kernel<32><<<1, 256, 0, stream>>>(psum, psq, 512, 1.f / (S1 * KNB), mean, rsv);
  norm_relu_kernel<32><<<dim3(2048, B_), 256, 0, stream>>>(bufB, mean, rsv, S1 * KNB * 32);
  linear_kernel<32, 32, 8, 32><<<dim3(512, B_), dim3(32, 8), 0, stream>>>(bufB, w1b, b1b, bufA, psum, psq, S1 * KNB);
  stats_kernel<32><<<1, 256, 0, stream>>>(psum, psq, 512, 1.f / (S1 * KNB), mean, rsv);
  norm_relu_kernel<32><<<dim3(2048, B_), 256, 0, stream>>>(bufA, mean, rsv, S1 * KNB * 32);
  linear_kernel<32, 32, 8, 32><<<dim3(512, B_), dim3(32, 8), 0, stream>>>(bufA, w1c, b1c, bufB, psum, psq, S1 * KNB);
  stats_kernel<32><<<1, 256, 0, stream>>>(psum, psq, 512, 1.f / (S1 * KNB), mean, rsv);
  norm_relu_kernel<32><<<dim3(2048, B_), 256, 0, stream>>>(bufB, mean, rsv, S1 * KNB * 32);
  pool1_kernel<<<dim3(512, B_), 256, 0, stream>>>(bufB, f1);

  // ---- stage 2 ----
  fps_kernel<S1, S2, false><<<B_, 512, 0, stream>>>(pc1, out4, pc2, out1);
  knn_kernel<S1, false><<<dim3(S2, B_), 128, 0, stream>>>(pc1, pc2, nidx2, S2);
  gather2_kernel<<<dim3(S2 * KNB / 256, B_), 256, 0, stream>>>(pc1, f1, nidx2, pc2, bufA);
  linear_kernel<35, 64, 4, 32><<<dim3(512, B_), dim3(64, 4), 0, stream>>>(bufA, w2a, b2a, bufB, psum, psq, S2 * KNB);
  stats_kernel<64><<<1, 256, 0, stream>>>(psum, psq, 512, 1.f / (S2 * KNB), mean, rsv);
  norm_relu_kernel<64><<<dim3(2048, B_), 256, 0, stream>>>(bufB, mean, rsv, S2 * KNB * 64);
  linear_kernel<64, 64, 4, 32><<<dim3(512, B_), dim3(64, 4), 0, stream>>>(bufB, w2b, b2b, bufA, psum, psq, S2 * KNB);
  stats_kernel<64><<<1, 256, 0, stream>>>(psum, psq, 512, 1.f / (S2 * KNB), mean, rsv);
  norm_relu_kernel<64><<<dim3(2048, B_), 256, 0, stream>>>(bufA, mean, rsv, S2 * KNB * 64);
  linear_kernel<64, 64, 4, 32><<<dim3(512, B_), dim3(64, 4), 0, stream>>>(bufA, w2c, b2c, bufB, psum, psq, S2 * KNB);
  stats_kernel<64><<<1, 256, 0, stream>>>(psum, psq, 512, 1.f / (S2 * KNB), mean, rsv);
  norm_relu_kernel<64><<<dim3(2048, B_), 256, 0, stream>>>(bufB, mean, rsv, S2 * KNB * 64);
  pool2_kernel<<<dim3(512, B_), 256, 0, stream>>>(bufB, out2);
}